// Round 5
// baseline (418.894 us; speedup 1.0000x reference)
//
#include <hip/hip_runtime.h>

// ---------------------------------------------------------------------------
// Fused single-head causal attention (B=4, S=2048, D=1024), fp32 in/out.
// Algebraic fold: out = P@(V@Wo)+... with Wvo=Wv@Wo precomputed, so the
// PV and output-projection GEMMs collapse into one (exact, bias2 as col-bias).
// Pipeline: bias2 -> cast q/k/v -> W transp(x3)+Wv cast -> Wvo gemm ->
// QKV' proj (q,k,vwo; XCD-swizzled) -> vwoT transp -> scores (triangular,
// XCD-swizzled) -> softmax (in-place bf16) -> final P@vwoT+bias2 -> d_out.
// GEMM: 128x128 tile, BK=64, global_load_lds both operands, XOR-swizzled LDS.
// ---------------------------------------------------------------------------

typedef __attribute__((ext_vector_type(8))) short bf16x8_t;   // 8 bf16 = 4 VGPR
typedef __attribute__((ext_vector_type(4))) float f32x4_t;    // MFMA acc

static __device__ __forceinline__ unsigned short f2b(float f) {
  union { float f; unsigned u; } c; c.f = f;
  unsigned u = c.u;
  u += 0x7fffu + ((u >> 16) & 1u);   // round-to-nearest-even
  return (unsigned short)(u >> 16);
}

static __device__ __forceinline__ void gload16(const void* g, const void* l) {
  __builtin_amdgcn_global_load_lds(
      (const __attribute__((address_space(1))) void*)g,
      (__attribute__((address_space(3))) void*)(void*)(unsigned short*)l,
      16, 0, 0);
}

// ---------------------------------------------------------------------------
// bias2[d] = bo[d] + sum_j bv[j] * Wo[j][d].  4 blocks, coalesced Wo rows.
// ---------------------------------------------------------------------------
__global__ __launch_bounds__(256)
void bias2_k(const float* __restrict__ bv, const float* __restrict__ Wo,
             const float* __restrict__ bo, float* __restrict__ bias2)
{
  const int d = blockIdx.x * 256 + threadIdx.x;   // 0..1023
  float s = bo[d];
#pragma unroll 8
  for (int j = 0; j < 1024; ++j) s += bv[j] * Wo[(size_t)j * 1024 + d];
  bias2[d] = s;
}

// ---------------------------------------------------------------------------
// Cast q,k,v fp32 -> bf16. grid (4096, 1, 3), 8 elems/thread.
// ---------------------------------------------------------------------------
__global__ __launch_bounds__(256)
void cast3_bf16(const float* __restrict__ q, const float* __restrict__ k,
                const float* __restrict__ v,
                unsigned short* __restrict__ oq, unsigned short* __restrict__ ok,
                unsigned short* __restrict__ ov)
{
  const int z = blockIdx.z;
  const float* in = z == 0 ? q : (z == 1 ? k : v);
  unsigned short* out = z == 0 ? oq : (z == 1 ? ok : ov);
  const size_t base = ((size_t)blockIdx.x * 256 + threadIdx.x) * 8;
  const float4 x0 = *(const float4*)(in + base);
  const float4 x1 = *(const float4*)(in + base + 4);
  union { unsigned u[4]; uint4 v4; } pk;
  pk.u[0] = f2b(x0.x) | ((unsigned)f2b(x0.y) << 16);
  pk.u[1] = f2b(x0.z) | ((unsigned)f2b(x0.w) << 16);
  pk.u[2] = f2b(x1.x) | ((unsigned)f2b(x1.y) << 16);
  pk.u[3] = f2b(x1.z) | ((unsigned)f2b(x1.w) << 16);
  *(uint4*)(out + base) = pk.v4;
}

// ---------------------------------------------------------------------------
// Weight prep: z=0 Wq^T, z=1 Wk^T, z=2 Wo^T (transpose+cast); z=3 Wv straight
// cast (row-major bf16, used as the Bt operand of the Wvo GEMM).
// ---------------------------------------------------------------------------
__global__ __launch_bounds__(256)
void prep_w(const float* __restrict__ wq, const float* __restrict__ wk,
            const float* __restrict__ wo, const float* __restrict__ wv,
            unsigned short* __restrict__ oq, unsigned short* __restrict__ ok,
            unsigned short* __restrict__ oo, unsigned short* __restrict__ ov)
{
  __shared__ unsigned short t[32][34];
  const int z = blockIdx.z;
  const float* in = z == 0 ? wq : (z == 1 ? wk : (z == 2 ? wo : wv));
  unsigned short* out = z == 0 ? oq : (z == 1 ? ok : (z == 2 ? oo : ov));
  const int bx = blockIdx.x, by = blockIdx.y;
  const int x = threadIdx.x, y = threadIdx.y;
  if (z == 3) {   // straight cast
#pragma unroll
    for (int yy = y; yy < 32; yy += 8) {
      const int r = by * 32 + yy, c = bx * 32 + x;
      out[(size_t)r * 1024 + c] = f2b(in[(size_t)r * 1024 + c]);
    }
    return;
  }
#pragma unroll
  for (int yy = y; yy < 32; yy += 8)
    t[yy][x] = f2b(in[(size_t)(by * 32 + yy) * 1024 + bx * 32 + x]);
  __syncthreads();
#pragma unroll
  for (int yy = y; yy < 32; yy += 8)
    out[(size_t)(bx * 32 + yy) * 1024 + by * 32 + x] = t[x][yy];
}

// ---------------------------------------------------------------------------
// GEMM body: 128x128 tile, BK=64, all-bf16 operands via global_load_lds.
// C[m,n] = scale*sum_k A[m,k]*Bt[n,k] (+bias[n] if bias!=null).
// LDS tile [128][64] bf16; 16B-chunk swizzle chunk^=row&7 applied to the
// GLOBAL source (linear LDS dest) and the ds_read addr (both-sides).
// 4 waves (2x2), 64x64 out each, 4x4 frags of 16x16x32 bf16 MFMA.
// ---------------------------------------------------------------------------
template<bool OUT_BF16>
static __device__ __forceinline__
void gemm_body(const unsigned short* __restrict__ Ab,
               const unsigned short* __restrict__ Bt,
               const float* __restrict__ bias, void* __restrict__ Cp,
               int kEnd, int lda, int ldb, int ldc, float scale, int bx, int by)
{
  __shared__ unsigned short As[128 * 64];  // 16 KB
  __shared__ unsigned short Bs[128 * 64];  // 16 KB

  const int tid  = threadIdx.x;
  const int lane = tid & 63;
  const int wid  = tid >> 6;
  const int wr   = wid >> 1, wc = wid & 1;
  const int l15  = lane & 15, l4 = lane >> 4;

  const int srow_l = lane >> 3;   // gload: lane -> row within 8-row group
  const int schk   = lane & 7;    // gload: 16B chunk

  f32x4_t acc[4][4];
#pragma unroll
  for (int m = 0; m < 4; ++m)
#pragma unroll
    for (int n = 0; n < 4; ++n) acc[m][n] = (f32x4_t){0.f, 0.f, 0.f, 0.f};

  for (int k0 = 0; k0 < kEnd; k0 += 64) {
#pragma unroll
    for (int i = 0; i < 4; ++i) {
      const int row = i * 32 + wid * 8 + srow_l;
      const size_t gr = (size_t)(by * 128 + row);
      const int g = schk ^ (row & 7);
      gload16(Ab + gr * lda + k0 + g * 8, &As[(i * 32 + wid * 8) * 64]);
    }
#pragma unroll
    for (int i = 0; i < 4; ++i) {
      const int row = i * 32 + wid * 8 + srow_l;
      const size_t gn = (size_t)(bx * 128 + row);
      const int g = schk ^ (row & 7);
      gload16(Bt + gn * ldb + k0 + g * 8, &Bs[(i * 32 + wid * 8) * 64]);
    }
    __syncthreads();

#pragma unroll
    for (int kk = 0; kk < 2; ++kk) {
      bf16x8_t a[4], b[4];
#pragma unroll
      for (int m = 0; m < 4; ++m) {
        const int row = wr * 64 + m * 16 + l15;
        const int c = (kk * 4 + l4) ^ (row & 7);
        a[m] = *(const bf16x8_t*)&As[row * 64 + c * 8];
      }
#pragma unroll
      for (int n = 0; n < 4; ++n) {
        const int row = wc * 64 + n * 16 + l15;
        const int c = (kk * 4 + l4) ^ (row & 7);
        b[n] = *(const bf16x8_t*)&Bs[row * 64 + c * 8];
      }
#pragma unroll
      for (int m = 0; m < 4; ++m)
#pragma unroll
        for (int n = 0; n < 4; ++n)
          acc[m][n] = __builtin_amdgcn_mfma_f32_16x16x32_bf16(a[m], b[n], acc[m][n], 0, 0, 0);
    }
    __syncthreads();
  }

  // epilogue: C/D layout col = lane&15, row = (lane>>4)*4 + j
  float*          Cf = (float*)Cp;
  unsigned short* Cb = (unsigned short*)Cp;
#pragma unroll
  for (int m = 0; m < 4; ++m)
#pragma unroll
    for (int n = 0; n < 4; ++n) {
      const int col = bx * 128 + wc * 64 + n * 16 + l15;
      const float bv = bias ? bias[col] : 0.f;
#pragma unroll
      for (int j = 0; j < 4; ++j) {
        const int row = by * 128 + wr * 64 + m * 16 + l4 * 4 + j;
        const float val = acc[m][n][j] * scale + bv;
        if (OUT_BF16) Cb[(size_t)row * ldc + col] = f2b(val);
        else          Cf[(size_t)row * ldc + col] = val;
      }
    }
}

// ---------------------------------------------------------------------------
// WvoT = (Wv@Wo)^T via C[m][n] = sum_j Wot[m][j] * Wvb[n][j].  64 blocks.
// ---------------------------------------------------------------------------
__global__ __launch_bounds__(256)
void gemm_wvo(const unsigned short* __restrict__ Wot,
              const unsigned short* __restrict__ Wvb,
              unsigned short* __restrict__ WvoT)
{
  gemm_body<true>(Wot, Wvb, nullptr, WvoT, 1024, 1024, 1024, 1024, 1.f,
                  blockIdx.x & 7, blockIdx.x >> 3);
}

// ---------------------------------------------------------------------------
// Fused QKV' projection, XCD-swizzled: z=0 q@Wq+bq, z=1 k@Wk+bk, z=2 v@Wvo.
// decode: xcd=d&7, j=d>>3, G=xcd*24+(j>>3) -> z=G/64, by=G%64, bx=j&7.
// ---------------------------------------------------------------------------
__global__ __launch_bounds__(256)
void gemm_qkv(const unsigned short* __restrict__ qi,
              const unsigned short* __restrict__ ki,
              const unsigned short* __restrict__ vi,
              const unsigned short* __restrict__ Wq,
              const unsigned short* __restrict__ Wk,
              const unsigned short* __restrict__ WvoT,
              const float* __restrict__ bq, const float* __restrict__ bk,
              unsigned short* __restrict__ oq, unsigned short* __restrict__ ok,
              unsigned short* __restrict__ ovwo)
{
  const int d = blockIdx.x;
  const int xcd = d & 7, j = d >> 3;
  const int G = xcd * 24 + (j >> 3);
  const int z = G >> 6;
  const int by = G & 63;
  const int bx = j & 7;
  const unsigned short* A = z == 0 ? qi : (z == 1 ? ki : vi);
  const unsigned short* B = z == 0 ? Wq : (z == 1 ? Wk : WvoT);
  const float* bias = z == 0 ? bq : (z == 1 ? bk : nullptr);
  unsigned short* C = z == 0 ? oq : (z == 1 ? ok : ovwo);
  gemm_body<true>(A, B, bias, C, 1024, 1024, 1024, 1024, 1.f, bx, by);
}

// ---------------------------------------------------------------------------
// Scores = q k^T / 32. 544 blocks = 8 XCD chunks x 68, triangular decode.
// ---------------------------------------------------------------------------
__global__ __launch_bounds__(256)
void gemm_scores(const unsigned short* __restrict__ Q,
                 const unsigned short* __restrict__ Kb, float* __restrict__ S)
{
  const int d = blockIdx.x;
  const int t = (d & 7) * 68 + (d >> 3);
  const int bz = t / 136;
  const int tri = t - bz * 136;
  int by = (int)((sqrtf(8.f * tri + 1.f) - 1.f) * 0.5f);
  while ((by + 1) * (by + 2) / 2 <= tri) ++by;
  while (by * (by + 1) / 2 > tri) --by;
  const int bx = tri - by * (by + 1) / 2;
  gemm_body<false>(Q + (size_t)bz * 2048 * 1024,
                   Kb + (size_t)bz * 2048 * 1024, nullptr,
                   S + (size_t)bz * 2048 * 2048,
                   1024, 1024, 1024, 2048, 0.03125f, bx, by);
}

// ---------------------------------------------------------------------------
// final = P @ vwoT + bias2 -> fp32 d_out. 512 blocks, XCD-swizzled,
// causal K-limit kEnd=(by+1)*128.
// ---------------------------------------------------------------------------
__global__ __launch_bounds__(256)
void gemm_final(const unsigned short* __restrict__ P,
                const unsigned short* __restrict__ VwoT,
                const float* __restrict__ bias2, float* __restrict__ out)
{
  const int d = blockIdx.x;
  const int xcd = d & 7, j = d >> 3;
  const int G = xcd * 8 + (j >> 3);
  const int bz = G >> 4;
  const int by = G & 15;
  const int bx = j & 7;
  const int kEnd = (by + 1) * 128;
  gemm_body<false>(P + (size_t)bz * 2048 * 4096,
                   VwoT + (size_t)bz * 1024 * 2048, bias2,
                   out + (size_t)bz * 2048 * 1024,
                   kEnd, 4096, 2048, 1024, 1.f, bx, by);
}

// ---------------------------------------------------------------------------
// vwo [B][S][D] bf16 -> vwoT [B][D][S] bf16
// ---------------------------------------------------------------------------
__global__ __launch_bounds__(256)
void transpose_v(const unsigned short* __restrict__ in, unsigned short* __restrict__ out)
{
  __shared__ unsigned short t[32][34];
  const int bx = blockIdx.x;   // col tile (D)
  const int by = blockIdx.y;   // row tile (S)
  const int bz = blockIdx.z;
  const int x = threadIdx.x, y = threadIdx.y;
  const unsigned short* inb = in + (size_t)bz * 2048 * 1024;
  unsigned short* ob = out + (size_t)bz * 1024 * 2048;
#pragma unroll
  for (int yy = y; yy < 32; yy += 8)
    t[yy][x] = inb[(size_t)(by * 32 + yy) * 1024 + bx * 32 + x];
  __syncthreads();
#pragma unroll
  for (int yy = y; yy < 32; yy += 8)
    ob[(size_t)(bx * 32 + yy) * 2048 + by * 32 + x] = t[x][yy];
}

// ---------------------------------------------------------------------------
// Causal row softmax, in-place, vectorized (float4 in, uint4 bf16 out).
// ---------------------------------------------------------------------------
__global__ __launch_bounds__(256)
void softmax_rows(const float* __restrict__ S, unsigned short* __restrict__ P)
{
  const int row = blockIdx.x;          // 0..8191  (= b*2048 + q)
  const int q = row & 2047;
  const float* srow = S + (size_t)row * 2048;
  unsigned short* prow = P + (size_t)row * 4096;
  const int nvalid = q + 1;
  const int kend = ((q >> 7) + 1) << 7;   // multiple of 128
  const int tid = threadIdx.x;
  const int wid = tid >> 6, lane = tid & 63;
  const int base = tid * 8;

  const float4 x0 = *(const float4*)(srow + base);
  const float4 x1 = *(const float4*)(srow + base + 4);
  float v[8] = {x0.x, x0.y, x0.z, x0.w, x1.x, x1.y, x1.z, x1.w};

  float m = -1e30f;
#pragma unroll
  for (int i = 0; i < 8; ++i) {
    if (base + i >= nvalid) v[i] = -1e30f;
    m = fmaxf(m, v[i]);
  }
#pragma unroll
  for (int off = 32; off > 0; off >>= 1) m = fmaxf(m, __shfl_xor(m, off));
  __shared__ float redm[4];
  __shared__ float reds[4];
  if (lane == 0) redm[wid] = m;
  __syncthreads();
  m = fmaxf(fmaxf(redm[0], redm[1]), fmaxf(redm[2], redm[3]));

  float s = 0.f;
  float e[8];
#pragma unroll
  for (int i = 0; i < 8; ++i) {
    e[i] = (base + i < nvalid) ? __expf(v[i] - m) : 0.f;
    s += e[i];
  }
#pragma unroll
  for (int off = 32; off > 0; off >>= 1) s += __shfl_xor(s, off);
  if (lane == 0) reds[wid] = s;
  __syncthreads();
  s = reds[0] + reds[1] + reds[2] + reds[3];
  const float inv = 1.f / s;

  if (base < kend) {
    union { unsigned u[4]; uint4 v4; } pk;
#pragma unroll
    for (int i = 0; i < 4; ++i) {
      const unsigned lo = f2b(e[2 * i] * inv);
      const unsigned hi = f2b(e[2 * i + 1] * inv);
      pk.u[i] = lo | (hi << 16);
    }
    *(uint4*)(prow + base) = pk.v4;
  }
}

// ---------------------------------------------------------------------------
extern "C" void kernel_launch(void* const* d_in, const int* in_sizes, int n_in,
                              void* d_out, int out_size, void* d_ws, size_t ws_size,
                              hipStream_t stream)
{
  const float* query = (const float*)d_in[0];
  const float* key   = (const float*)d_in[1];
  const float* value = (const float*)d_in[2];
  const float* Wq    = (const float*)d_in[3];
  const float* bq    = (const float*)d_in[4];
  const float* Wk    = (const float*)d_in[5];
  const float* bk    = (const float*)d_in[6];
  const float* Wv    = (const float*)d_in[7];
  const float* bv    = (const float*)d_in[8];
  const float* Wo    = (const float*)d_in[9];
  const float* bo    = (const float*)d_in[10];
  float* out = (float*)d_out;

  char* ws = (char*)d_ws;
  const size_t MB = 1024 * 1024;
  unsigned short* Wqt   = (unsigned short*)(ws + 0 * MB);
  unsigned short* Wkt   = (unsigned short*)(ws + 2 * MB);
  unsigned short* Wot   = (unsigned short*)(ws + 4 * MB);
  unsigned short* Wvb   = (unsigned short*)(ws + 6 * MB);
  unsigned short* WvoT  = (unsigned short*)(ws + 8 * MB);
  float*          bias2 = (float*)(ws + 10 * MB);
  unsigned short* qbuf  = (unsigned short*)(ws + 12 * MB);  // 16 MB
  unsigned short* kbuf  = (unsigned short*)(ws + 28 * MB);  // 16 MB
  unsigned short* vwo   = (unsigned short*)(ws + 44 * MB);  // 16 MB
  unsigned short* vwoT  = (unsigned short*)(ws + 60 * MB);  // 16 MB
  float*          Sraw  = (float*)(ws + 80 * MB);           // 64 MB
  // cast outputs alias Sraw (dead before gemm_scores writes it)
  unsigned short* qin   = (unsigned short*)(ws + 80 * MB);
  unsigned short* kin   = (unsigned short*)(ws + 96 * MB);
  unsigned short* vin   = (unsigned short*)(ws + 112 * MB);

  // 1) bias2 = bv@Wo + bo (fp32 inputs, no deps)
  bias2_k<<<4, 256, 0, stream>>>(bv, Wo, bo, bias2);

  // 2) cast q/k/v fp32 -> bf16
  cast3_bf16<<<dim3(4096, 1, 3), 256, 0, stream>>>(query, key, value, qin, kin, vin);

  // 3) weight prep: Wq^T, Wk^T, Wo^T, Wv straight cast
  prep_w<<<dim3(32, 32, 4), dim3(32, 8), 0, stream>>>(
      Wq, Wk, Wo, Wv, Wqt, Wkt, Wot, Wvb);

  // 4) WvoT = (Wv@Wo)^T
  gemm_wvo<<<64, 256, 0, stream>>>(Wot, Wvb, WvoT);

  // 5) fused projections: q@Wq+bq, k@Wk+bk, v@Wvo (XCD-swizzled)
  gemm_qkv<<<1536, 256, 0, stream>>>(
      qin, kin, vin, Wqt, Wkt, WvoT, bq, bk, qbuf, kbuf, vwo);

  // 6) vwo -> vwoT [B][D][S]
  transpose_v<<<dim3(32, 64, 4), dim3(32, 8), 0, stream>>>(vwo, vwoT);

  // 7) scores = q k^T / 32 (packed triangular, XCD-swizzled), fp32
  gemm_scores<<<544, 256, 0, stream>>>(qbuf, kbuf, Sraw);

  // 8) causal softmax, in-place P (bf16) over Sraw
  softmax_rows<<<8192, 256, 0, stream>>>(Sraw, (unsigned short*)Sraw);

  // 9) out = P @ vwoT + bias2 -> fp32 d_out (causal K-limit, XCD-swizzled)
  gemm_final<<<512, 256, 0, stream>>>((unsigned short*)Sraw, vwoT, bias2, out);
}

// Round 6
// 361.265 us; speedup vs baseline: 1.1595x; 1.1595x over previous
//
#include <hip/hip_runtime.h>

// ---------------------------------------------------------------------------
// Fused single-head causal attention (B=4, S=2048, D=1024), fp32 in/out.
// Algebraic fold: out = P@(V@Wvo)+bias2, Wvo=Wv@Wo, bias2=bv@Wo+bo (exact).
// Pipeline: cast q/k/v -> W prep -> bias2 (wide GEMV) -> Wvo gemm ->
// QKV' proj (q,k,vwo; XCD-swizzled) -> vwoT transp -> scores (triangular,
// XCD-swizzled) -> softmax (in-place bf16) -> final P@vwoT+bias2 -> d_out.
// GEMM: 128x128 tile, BK=64, global_load_lds both operands, XOR-swizzled LDS.
// ---------------------------------------------------------------------------

typedef __attribute__((ext_vector_type(8))) short bf16x8_t;   // 8 bf16 = 4 VGPR
typedef __attribute__((ext_vector_type(4))) float f32x4_t;    // MFMA acc

static __device__ __forceinline__ unsigned short f2b(float f) {
  union { float f; unsigned u; } c; c.f = f;
  unsigned u = c.u;
  u += 0x7fffu + ((u >> 16) & 1u);   // round-to-nearest-even
  return (unsigned short)(u >> 16);
}

static __device__ __forceinline__ void gload16(const void* g, const void* l) {
  __builtin_amdgcn_global_load_lds(
      (const __attribute__((address_space(1))) void*)g,
      (__attribute__((address_space(3))) void*)(void*)(unsigned short*)l,
      16, 0, 0);
}

// ---------------------------------------------------------------------------
// bias2[d] = bo[d] + sum_j bv[j]*Wo[j][d].  Wide-parallel GEMV: 64 blocks,
// block b owns cols [b*16,b*16+16), 256 thr = 16 cols x 16 row-groups,
// coalesced 64B row segments, LDS tree-reduce. (R5's 4-block version was
// ~150us latency-bound — 4/256 CUs. This is ~5us.)
// ---------------------------------------------------------------------------
__global__ __launch_bounds__(256)
void bias2_k(const float* __restrict__ bv, const float* __restrict__ Wo,
             const float* __restrict__ bo, float* __restrict__ bias2)
{
  __shared__ float red[16][17];
  const int ci = threadIdx.x & 15;
  const int rg = threadIdx.x >> 4;
  const int col = blockIdx.x * 16 + ci;
  float s = 0.f;
#pragma unroll 4
  for (int r = rg; r < 1024; r += 16)
    s += bv[r] * Wo[(size_t)r * 1024 + col];
  red[rg][ci] = s;
  __syncthreads();
  if (rg == 0) {
    float t = 0.f;
#pragma unroll
    for (int i = 0; i < 16; ++i) t += red[i][ci];
    bias2[col] = t + bo[col];
  }
}

// ---------------------------------------------------------------------------
// Cast q,k,v fp32 -> bf16. grid (4096, 1, 3), 8 elems/thread.
// ---------------------------------------------------------------------------
__global__ __launch_bounds__(256)
void cast3_bf16(const float* __restrict__ q, const float* __restrict__ k,
                const float* __restrict__ v,
                unsigned short* __restrict__ oq, unsigned short* __restrict__ ok,
                unsigned short* __restrict__ ov)
{
  const int z = blockIdx.z;
  const float* in = z == 0 ? q : (z == 1 ? k : v);
  unsigned short* out = z == 0 ? oq : (z == 1 ? ok : ov);
  const size_t base = ((size_t)blockIdx.x * 256 + threadIdx.x) * 8;
  const float4 x0 = *(const float4*)(in + base);
  const float4 x1 = *(const float4*)(in + base + 4);
  union { unsigned u[4]; uint4 v4; } pk;
  pk.u[0] = f2b(x0.x) | ((unsigned)f2b(x0.y) << 16);
  pk.u[1] = f2b(x0.z) | ((unsigned)f2b(x0.w) << 16);
  pk.u[2] = f2b(x1.x) | ((unsigned)f2b(x1.y) << 16);
  pk.u[3] = f2b(x1.z) | ((unsigned)f2b(x1.w) << 16);
  *(uint4*)(out + base) = pk.v4;
}

// ---------------------------------------------------------------------------
// Weight prep: z=0 Wq^T, z=1 Wk^T, z=2 Wo^T (transpose+cast); z=3 Wv straight
// cast (row-major bf16, Bt operand of the Wvo GEMM).
// ---------------------------------------------------------------------------
__global__ __launch_bounds__(256)
void prep_w(const float* __restrict__ wq, const float* __restrict__ wk,
            const float* __restrict__ wo, const float* __restrict__ wv,
            unsigned short* __restrict__ oq, unsigned short* __restrict__ ok,
            unsigned short* __restrict__ oo, unsigned short* __restrict__ ov)
{
  __shared__ unsigned short t[32][34];
  const int z = blockIdx.z;
  const float* in = z == 0 ? wq : (z == 1 ? wk : (z == 2 ? wo : wv));
  unsigned short* out = z == 0 ? oq : (z == 1 ? ok : (z == 2 ? oo : ov));
  const int bx = blockIdx.x, by = blockIdx.y;
  const int x = threadIdx.x, y = threadIdx.y;
  if (z == 3) {   // straight cast
#pragma unroll
    for (int yy = y; yy < 32; yy += 8) {
      const int r = by * 32 + yy, c = bx * 32 + x;
      out[(size_t)r * 1024 + c] = f2b(in[(size_t)r * 1024 + c]);
    }
    return;
  }
#pragma unroll
  for (int yy = y; yy < 32; yy += 8)
    t[yy][x] = f2b(in[(size_t)(by * 32 + yy) * 1024 + bx * 32 + x]);
  __syncthreads();
#pragma unroll
  for (int yy = y; yy < 32; yy += 8)
    out[(size_t)(bx * 32 + yy) * 1024 + by * 32 + x] = t[x][yy];
}

// ---------------------------------------------------------------------------
// GEMM body: 128x128 tile, BK=64, all-bf16 operands via global_load_lds.
// C[m,n] = scale*sum_k A[m,k]*Bt[n,k] (+bias[n] if bias!=null).
// LDS tile [128][64] bf16; 16B-chunk swizzle chunk^=row&7 applied to the
// GLOBAL source (linear LDS dest) and the ds_read addr (both-sides).
// 4 waves (2x2), 64x64 out each, 4x4 frags of 16x16x32 bf16 MFMA.
// ---------------------------------------------------------------------------
template<bool OUT_BF16>
static __device__ __forceinline__
void gemm_body(const unsigned short* __restrict__ Ab,
               const unsigned short* __restrict__ Bt,
               const float* __restrict__ bias, void* __restrict__ Cp,
               int kEnd, int lda, int ldb, int ldc, float scale, int bx, int by)
{
  __shared__ unsigned short As[128 * 64];  // 16 KB
  __shared__ unsigned short Bs[128 * 64];  // 16 KB

  const int tid  = threadIdx.x;
  const int lane = tid & 63;
  const int wid  = tid >> 6;
  const int wr   = wid >> 1, wc = wid & 1;
  const int l15  = lane & 15, l4 = lane >> 4;

  const int srow_l = lane >> 3;   // gload: lane -> row within 8-row group
  const int schk   = lane & 7;    // gload: 16B chunk

  f32x4_t acc[4][4];
#pragma unroll
  for (int m = 0; m < 4; ++m)
#pragma unroll
    for (int n = 0; n < 4; ++n) acc[m][n] = (f32x4_t){0.f, 0.f, 0.f, 0.f};

  for (int k0 = 0; k0 < kEnd; k0 += 64) {
#pragma unroll
    for (int i = 0; i < 4; ++i) {
      const int row = i * 32 + wid * 8 + srow_l;
      const size_t gr = (size_t)(by * 128 + row);
      const int g = schk ^ (row & 7);
      gload16(Ab + gr * lda + k0 + g * 8, &As[(i * 32 + wid * 8) * 64]);
    }
#pragma unroll
    for (int i = 0; i < 4; ++i) {
      const int row = i * 32 + wid * 8 + srow_l;
      const size_t gn = (size_t)(bx * 128 + row);
      const int g = schk ^ (row & 7);
      gload16(Bt + gn * ldb + k0 + g * 8, &Bs[(i * 32 + wid * 8) * 64]);
    }
    __syncthreads();

#pragma unroll
    for (int kk = 0; kk < 2; ++kk) {
      bf16x8_t a[4], b[4];
#pragma unroll
      for (int m = 0; m < 4; ++m) {
        const int row = wr * 64 + m * 16 + l15;
        const int c = (kk * 4 + l4) ^ (row & 7);
        a[m] = *(const bf16x8_t*)&As[row * 64 + c * 8];
      }
#pragma unroll
      for (int n = 0; n < 4; ++n) {
        const int row = wc * 64 + n * 16 + l15;
        const int c = (kk * 4 + l4) ^ (row & 7);
        b[n] = *(const bf16x8_t*)&Bs[row * 64 + c * 8];
      }
#pragma unroll
      for (int m = 0; m < 4; ++m)
#pragma unroll
        for (int n = 0; n < 4; ++n)
          acc[m][n] = __builtin_amdgcn_mfma_f32_16x16x32_bf16(a[m], b[n], acc[m][n], 0, 0, 0);
    }
    __syncthreads();
  }

  // epilogue: C/D layout col = lane&15, row = (lane>>4)*4 + j
  float*          Cf = (float*)Cp;
  unsigned short* Cb = (unsigned short*)Cp;
#pragma unroll
  for (int m = 0; m < 4; ++m)
#pragma unroll
    for (int n = 0; n < 4; ++n) {
      const int col = bx * 128 + wc * 64 + n * 16 + l15;
      const float bv = bias ? bias[col] : 0.f;
#pragma unroll
      for (int j = 0; j < 4; ++j) {
        const int row = by * 128 + wr * 64 + m * 16 + l4 * 4 + j;
        const float val = acc[m][n][j] * scale + bv;
        if (OUT_BF16) Cb[(size_t)row * ldc + col] = f2b(val);
        else          Cf[(size_t)row * ldc + col] = val;
      }
    }
}

// ---------------------------------------------------------------------------
// WvoT = (Wv@Wo)^T via C[m][n] = sum_j Wot[m][j] * Wvb[n][j].  64 blocks.
// ---------------------------------------------------------------------------
__global__ __launch_bounds__(256)
void gemm_wvo(const unsigned short* __restrict__ Wot,
              const unsigned short* __restrict__ Wvb,
              unsigned short* __restrict__ WvoT)
{
  gemm_body<true>(Wot, Wvb, nullptr, WvoT, 1024, 1024, 1024, 1024, 1.f,
                  blockIdx.x & 7, blockIdx.x >> 3);
}

// ---------------------------------------------------------------------------
// Fused QKV' projection, XCD-swizzled: z=0 q@Wq+bq, z=1 k@Wk+bk, z=2 v@Wvo.
// decode: xcd=d&7, j=d>>3, G=xcd*24+(j>>3) -> z=G/64, by=G%64, bx=j&7.
// ---------------------------------------------------------------------------
__global__ __launch_bounds__(256)
void gemm_qkv(const unsigned short* __restrict__ qi,
              const unsigned short* __restrict__ ki,
              const unsigned short* __restrict__ vi,
              const unsigned short* __restrict__ Wq,
              const unsigned short* __restrict__ Wk,
              const unsigned short* __restrict__ WvoT,
              const float* __restrict__ bq, const float* __restrict__ bk,
              unsigned short* __restrict__ oq, unsigned short* __restrict__ ok,
              unsigned short* __restrict__ ovwo)
{
  const int d = blockIdx.x;
  const int xcd = d & 7, j = d >> 3;
  const int G = xcd * 24 + (j >> 3);
  const int z = G >> 6;
  const int by = G & 63;
  const int bx = j & 7;
  const unsigned short* A = z == 0 ? qi : (z == 1 ? ki : vi);
  const unsigned short* B = z == 0 ? Wq : (z == 1 ? Wk : WvoT);
  const float* bias = z == 0 ? bq : (z == 1 ? bk : nullptr);
  unsigned short* C = z == 0 ? oq : (z == 1 ? ok : ovwo);
  gemm_body<true>(A, B, bias, C, 1024, 1024, 1024, 1024, 1.f, bx, by);
}

// ---------------------------------------------------------------------------
// Scores = q k^T / 32. 544 blocks = 8 XCD chunks x 68, triangular decode.
// ---------------------------------------------------------------------------
__global__ __launch_bounds__(256)
void gemm_scores(const unsigned short* __restrict__ Q,
                 const unsigned short* __restrict__ Kb, float* __restrict__ S)
{
  const int d = blockIdx.x;
  const int t = (d & 7) * 68 + (d >> 3);
  const int bz = t / 136;
  const int tri = t - bz * 136;
  int by = (int)((sqrtf(8.f * tri + 1.f) - 1.f) * 0.5f);
  while ((by + 1) * (by + 2) / 2 <= tri) ++by;
  while (by * (by + 1) / 2 > tri) --by;
  const int bx = tri - by * (by + 1) / 2;
  gemm_body<false>(Q + (size_t)bz * 2048 * 1024,
                   Kb + (size_t)bz * 2048 * 1024, nullptr,
                   S + (size_t)bz * 2048 * 2048,
                   1024, 1024, 1024, 2048, 0.03125f, bx, by);
}

// ---------------------------------------------------------------------------
// final = P @ vwoT + bias2 -> fp32 d_out. 512 blocks, XCD-swizzled,
// causal K-limit kEnd=(by+1)*128.
// ---------------------------------------------------------------------------
__global__ __launch_bounds__(256)
void gemm_final(const unsigned short* __restrict__ P,
                const unsigned short* __restrict__ VwoT,
                const float* __restrict__ bias2, float* __restrict__ out)
{
  const int d = blockIdx.x;
  const int xcd = d & 7, j = d >> 3;
  const int G = xcd * 8 + (j >> 3);
  const int bz = G >> 4;
  const int by = G & 15;
  const int bx = j & 7;
  const int kEnd = (by + 1) * 128;
  gemm_body<false>(P + (size_t)bz * 2048 * 4096,
                   VwoT + (size_t)bz * 1024 * 2048, bias2,
                   out + (size_t)bz * 2048 * 1024,
                   kEnd, 4096, 2048, 1024, 1.f, bx, by);
}

// ---------------------------------------------------------------------------
// vwo [B][S][D] bf16 -> vwoT [B][D][S] bf16
// ---------------------------------------------------------------------------
__global__ __launch_bounds__(256)
void transpose_v(const unsigned short* __restrict__ in, unsigned short* __restrict__ out)
{
  __shared__ unsigned short t[32][34];
  const int bx = blockIdx.x;   // col tile (D)
  const int by = blockIdx.y;   // row tile (S)
  const int bz = blockIdx.z;
  const int x = threadIdx.x, y = threadIdx.y;
  const unsigned short* inb = in + (size_t)bz * 2048 * 1024;
  unsigned short* ob = out + (size_t)bz * 1024 * 2048;
#pragma unroll
  for (int yy = y; yy < 32; yy += 8)
    t[yy][x] = inb[(size_t)(by * 32 + yy) * 1024 + bx * 32 + x];
  __syncthreads();
#pragma unroll
  for (int yy = y; yy < 32; yy += 8)
    ob[(size_t)(bx * 32 + yy) * 2048 + by * 32 + x] = t[x][yy];
}

// ---------------------------------------------------------------------------
// Causal row softmax, in-place, vectorized (float4 in, uint4 bf16 out).
// ---------------------------------------------------------------------------
__global__ __launch_bounds__(256)
void softmax_rows(const float* __restrict__ S, unsigned short* __restrict__ P)
{
  const int row = blockIdx.x;          // 0..8191  (= b*2048 + q)
  const int q = row & 2047;
  const float* srow = S + (size_t)row * 2048;
  unsigned short* prow = P + (size_t)row * 4096;
  const int nvalid = q + 1;
  const int kend = ((q >> 7) + 1) << 7;   // multiple of 128
  const int tid = threadIdx.x;
  const int wid = tid >> 6, lane = tid & 63;
  const int base = tid * 8;

  const float4 x0 = *(const float4*)(srow + base);
  const float4 x1 = *(const float4*)(srow + base + 4);
  float v[8] = {x0.x, x0.y, x0.z, x0.w, x1.x, x1.y, x1.z, x1.w};

  float m = -1e30f;
#pragma unroll
  for (int i = 0; i < 8; ++i) {
    if (base + i >= nvalid) v[i] = -1e30f;
    m = fmaxf(m, v[i]);
  }
#pragma unroll
  for (int off = 32; off > 0; off >>= 1) m = fmaxf(m, __shfl_xor(m, off));
  __shared__ float redm[4];
  __shared__ float reds[4];
  if (lane == 0) redm[wid] = m;
  __syncthreads();
  m = fmaxf(fmaxf(redm[0], redm[1]), fmaxf(redm[2], redm[3]));

  float s = 0.f;
  float e[8];
#pragma unroll
  for (int i = 0; i < 8; ++i) {
    e[i] = (base + i < nvalid) ? __expf(v[i] - m) : 0.f;
    s += e[i];
  }
#pragma unroll
  for (int off = 32; off > 0; off >>= 1) s += __shfl_xor(s, off);
  if (lane == 0) reds[wid] = s;
  __syncthreads();
  s = reds[0] + reds[1] + reds[2] + reds[3];
  const float inv = 1.f / s;

  if (base < kend) {
    union { unsigned u[4]; uint4 v4; } pk;
#pragma unroll
    for (int i = 0; i < 4; ++i) {
      const unsigned lo = f2b(e[2 * i] * inv);
      const unsigned hi = f2b(e[2 * i + 1] * inv);
      pk.u[i] = lo | (hi << 16);
    }
    *(uint4*)(prow + base) = pk.v4;
  }
}

// ---------------------------------------------------------------------------
extern "C" void kernel_launch(void* const* d_in, const int* in_sizes, int n_in,
                              void* d_out, int out_size, void* d_ws, size_t ws_size,
                              hipStream_t stream)
{
  const float* query = (const float*)d_in[0];
  const float* key   = (const float*)d_in[1];
  const float* value = (const float*)d_in[2];
  const float* Wq    = (const float*)d_in[3];
  const float* bq    = (const float*)d_in[4];
  const float* Wk    = (const float*)d_in[5];
  const float* bk    = (const float*)d_in[6];
  const float* Wv    = (const float*)d_in[7];
  const float* bv    = (const float*)d_in[8];
  const float* Wo    = (const float*)d_in[9];
  const float* bo    = (const float*)d_in[10];
  float* out = (float*)d_out;

  char* ws = (char*)d_ws;
  const size_t MB = 1024 * 1024;
  unsigned short* Wqt   = (unsigned short*)(ws + 0 * MB);
  unsigned short* Wkt   = (unsigned short*)(ws + 2 * MB);
  unsigned short* Wot   = (unsigned short*)(ws + 4 * MB);
  unsigned short* Wvb   = (unsigned short*)(ws + 6 * MB);
  unsigned short* WvoT  = (unsigned short*)(ws + 8 * MB);
  float*          bias2 = (float*)(ws + 10 * MB);
  unsigned short* qbuf  = (unsigned short*)(ws + 12 * MB);  // 16 MB
  unsigned short* kbuf  = (unsigned short*)(ws + 28 * MB);  // 16 MB
  unsigned short* vwo   = (unsigned short*)(ws + 44 * MB);  // 16 MB
  unsigned short* vwoT  = (unsigned short*)(ws + 60 * MB);  // 16 MB
  float*          Sraw  = (float*)(ws + 80 * MB);           // 64 MB
  // cast outputs alias Sraw (dead before gemm_scores writes it)
  unsigned short* qin   = (unsigned short*)(ws + 80 * MB);
  unsigned short* kin   = (unsigned short*)(ws + 96 * MB);
  unsigned short* vin   = (unsigned short*)(ws + 112 * MB);

  // 1) cast q/k/v fp32 -> bf16
  cast3_bf16<<<dim3(4096, 1, 3), 256, 0, stream>>>(query, key, value, qin, kin, vin);

  // 2) weight prep: Wq^T, Wk^T, Wo^T, Wv straight cast
  prep_w<<<dim3(32, 32, 4), dim3(32, 8), 0, stream>>>(
      Wq, Wk, Wo, Wv, Wqt, Wkt, Wot, Wvb);

  // 3) bias2 = bv@Wo + bo (wide-parallel GEMV, 64 blocks)
  bias2_k<<<64, 256, 0, stream>>>(bv, Wo, bo, bias2);

  // 4) WvoT = (Wv@Wo)^T
  gemm_wvo<<<64, 256, 0, stream>>>(Wot, Wvb, WvoT);

  // 5) fused projections: q@Wq+bq, k@Wk+bk, v@Wvo (XCD-swizzled)
  gemm_qkv<<<1536, 256, 0, stream>>>(
      qin, kin, vin, Wqt, Wkt, WvoT, bq, bk, qbuf, kbuf, vwo);

  // 6) vwo -> vwoT [B][D][S]
  transpose_v<<<dim3(32, 64, 4), dim3(32, 8), 0, stream>>>(vwo, vwoT);

  // 7) scores = q k^T / 32 (packed triangular, XCD-swizzled), fp32
  gemm_scores<<<544, 256, 0, stream>>>(qbuf, kbuf, Sraw);

  // 8) causal softmax, in-place P (bf16) over Sraw
  softmax_rows<<<8192, 256, 0, stream>>>(Sraw, (unsigned short*)Sraw);

  // 9) out = P @ vwoT + bias2 -> fp32 d_out (causal K-limit, XCD-swizzled)
  gemm_final<<<512, 256, 0, stream>>>((unsigned short*)Sraw, vwoT, bias2, out);
}

// Round 8
// 332.311 us; speedup vs baseline: 1.2605x; 1.0871x over previous
//
#include <hip/hip_runtime.h>

// ---------------------------------------------------------------------------
// Fused single-head causal attention (B=4, S=2048, D=1024), fp32 in/out.
// Folds: Wvo=Wv@Wo, bias2=bv@Wo+bo  =>  out = P@(v@Wvo)+bias2 (exact).
// No-max softmax: E=exp(s) in scores epilogue (s bounded ~|8|), rowsum via
// atomicAdd, normalization folded into final GEMM epilogue.
// vT produced directly by GEMM (A=WvoT, Bt=v) — no transpose kernel.
// 6 dispatches: prep_all -> wvo_bias2 -> qkv3 -> scores -> final (+memset).
// GEMM: 128x128 tile, BK=64, global_load_lds both operands, XOR-swizzled LDS.
// ---------------------------------------------------------------------------

typedef __attribute__((ext_vector_type(8))) short bf16x8_t;   // 8 bf16 = 4 VGPR
typedef __attribute__((ext_vector_type(4))) float f32x4_t;    // MFMA acc

static __device__ __forceinline__ unsigned short f2b(float f) {
  union { float f; unsigned u; } c; c.f = f;
  unsigned u = c.u;
  u += 0x7fffu + ((u >> 16) & 1u);   // round-to-nearest-even
  return (unsigned short)(u >> 16);
}

static __device__ __forceinline__ void gload16(const void* g, const void* l) {
  __builtin_amdgcn_global_load_lds(
      (const __attribute__((address_space(1))) void*)g,
      (__attribute__((address_space(3))) void*)(void*)(unsigned short*)l,
      16, 0, 0);
}

// ---------------------------------------------------------------------------
// prep_all: merged input casts + weight prep.
//  d < 12288 : cast q/k/v fp32->bf16 (z=d>>12, 8 elem/thread)
//  d >= 12288: t=d-12288; z=t>>10: 0=Wq^T,1=Wk^T,2=Wo^T (transpose+cast),
//              3=Wv straight cast.
// ---------------------------------------------------------------------------
__global__ __launch_bounds__(256)
void prep_all(const float* __restrict__ q, const float* __restrict__ k,
              const float* __restrict__ v,
              unsigned short* __restrict__ qin, unsigned short* __restrict__ kin,
              unsigned short* __restrict__ vin,
              const float* __restrict__ wq, const float* __restrict__ wk,
              const float* __restrict__ wo, const float* __restrict__ wv,
              unsigned short* __restrict__ oq, unsigned short* __restrict__ ok,
              unsigned short* __restrict__ oo, unsigned short* __restrict__ ov)
{
  __shared__ unsigned short t[32][34];
  const int d = blockIdx.x;
  const int tid = threadIdx.x;
  if (d < 12288) {
    const int z = d >> 12;
    const int blk = d & 4095;
    const float* in = z == 0 ? q : (z == 1 ? k : v);
    unsigned short* out = z == 0 ? qin : (z == 1 ? kin : vin);
    const size_t base = ((size_t)blk * 256 + tid) * 8;
    const float4 x0 = *(const float4*)(in + base);
    const float4 x1 = *(const float4*)(in + base + 4);
    union { unsigned u[4]; uint4 v4; } pk;
    pk.u[0] = f2b(x0.x) | ((unsigned)f2b(x0.y) << 16);
    pk.u[1] = f2b(x0.z) | ((unsigned)f2b(x0.w) << 16);
    pk.u[2] = f2b(x1.x) | ((unsigned)f2b(x1.y) << 16);
    pk.u[3] = f2b(x1.z) | ((unsigned)f2b(x1.w) << 16);
    *(uint4*)(out + base) = pk.v4;
    return;
  }
  const int tt = d - 12288;
  const int z = tt >> 10;
  const int r = tt & 1023;
  const int by = r >> 5, bx = r & 31;
  const int x = tid & 31, y = tid >> 5;
  const float* in = z == 0 ? wq : (z == 1 ? wk : (z == 2 ? wo : wv));
  unsigned short* out = z == 0 ? oq : (z == 1 ? ok : (z == 2 ? oo : ov));
  if (z == 3) {   // straight cast
#pragma unroll
    for (int yy = y; yy < 32; yy += 8) {
      const int rr = by * 32 + yy, cc = bx * 32 + x;
      out[(size_t)rr * 1024 + cc] = f2b(in[(size_t)rr * 1024 + cc]);
    }
    return;
  }
#pragma unroll
  for (int yy = y; yy < 32; yy += 8)
    t[yy][x] = f2b(in[(size_t)(by * 32 + yy) * 1024 + bx * 32 + x]);
  __syncthreads();
#pragma unroll
  for (int yy = y; yy < 32; yy += 8)
    out[(size_t)(bx * 32 + yy) * 1024 + by * 32 + x] = t[x][yy];
}

// ---------------------------------------------------------------------------
// GEMM body: 128x128 tile, BK=64, all-bf16 operands via global_load_lds.
// MODE 0: C = scale*A·Bt^T (+bias), OUT_BF16 selects dtype.
// MODE 1: scores-exp: Cb = bf16(exp(acc*scale)) causal-masked (col<=row),
//         per-row partial sums atomicAdd'ed into rowsum[]. (OUT ignored=bf16)
// MODE 2: final-norm: Cf = acc/rowsum[row] + bias[col]  (fp32 out).
// LDS tile [128][64] bf16; 16B-chunk swizzle chunk^=row&7 on BOTH the global
// source (gload_lds writes linearly) and the ds_read address.
// 4 waves (2x2), 64x64 out each, 4x4 frags of 16x16x32 bf16 MFMA.
// ---------------------------------------------------------------------------
template<bool OUT_BF16, int MODE>
static __device__ __forceinline__
void gemm_body(const unsigned short* __restrict__ Ab,
               const unsigned short* __restrict__ Bt,
               const float* __restrict__ bias, void* __restrict__ Cp,
               float* __restrict__ rowsum,
               int kEnd, int lda, int ldb, int ldc, float scale, int bx, int by)
{
  __shared__ unsigned short As[128 * 64];  // 16 KB
  __shared__ unsigned short Bs[128 * 64];  // 16 KB

  const int tid  = threadIdx.x;
  const int lane = tid & 63;
  const int wid  = tid >> 6;
  const int wr   = wid >> 1, wc = wid & 1;
  const int l15  = lane & 15, l4 = lane >> 4;

  const int srow_l = lane >> 3;   // gload: lane -> row within 8-row group
  const int schk   = lane & 7;    // gload: 16B chunk

  f32x4_t acc[4][4];
#pragma unroll
  for (int m = 0; m < 4; ++m)
#pragma unroll
    for (int n = 0; n < 4; ++n) acc[m][n] = (f32x4_t){0.f, 0.f, 0.f, 0.f};

  for (int k0 = 0; k0 < kEnd; k0 += 64) {
#pragma unroll
    for (int i = 0; i < 4; ++i) {
      const int row = i * 32 + wid * 8 + srow_l;
      const size_t gr = (size_t)(by * 128 + row);
      const int g = schk ^ (row & 7);
      gload16(Ab + gr * lda + k0 + g * 8, &As[(i * 32 + wid * 8) * 64]);
    }
#pragma unroll
    for (int i = 0; i < 4; ++i) {
      const int row = i * 32 + wid * 8 + srow_l;
      const size_t gn = (size_t)(bx * 128 + row);
      const int g = schk ^ (row & 7);
      gload16(Bt + gn * ldb + k0 + g * 8, &Bs[(i * 32 + wid * 8) * 64]);
    }
    __syncthreads();

#pragma unroll
    for (int kk = 0; kk < 2; ++kk) {
      bf16x8_t a[4], b[4];
#pragma unroll
      for (int m = 0; m < 4; ++m) {
        const int row = wr * 64 + m * 16 + l15;
        const int c = (kk * 4 + l4) ^ (row & 7);
        a[m] = *(const bf16x8_t*)&As[row * 64 + c * 8];
      }
#pragma unroll
      for (int n = 0; n < 4; ++n) {
        const int row = wc * 64 + n * 16 + l15;
        const int c = (kk * 4 + l4) ^ (row & 7);
        b[n] = *(const bf16x8_t*)&Bs[row * 64 + c * 8];
      }
#pragma unroll
      for (int m = 0; m < 4; ++m)
#pragma unroll
        for (int n = 0; n < 4; ++n)
          acc[m][n] = __builtin_amdgcn_mfma_f32_16x16x32_bf16(a[m], b[n], acc[m][n], 0, 0, 0);
    }
    __syncthreads();
  }

  // epilogue: C/D layout col = lane&15, row = (lane>>4)*4 + j
  float*          Cf = (float*)Cp;
  unsigned short* Cb = (unsigned short*)Cp;
  if constexpr (MODE == 1) {
#pragma unroll
    for (int m = 0; m < 4; ++m)
#pragma unroll
      for (int j = 0; j < 4; ++j) {
        const int row = by * 128 + wr * 64 + m * 16 + l4 * 4 + j;
        float rsum = 0.f;
#pragma unroll
        for (int n = 0; n < 4; ++n) {
          const int col = bx * 128 + wc * 64 + n * 16 + l15;
          const float e = (col <= row) ? __expf(acc[m][n][j] * scale) : 0.f;
          Cb[(size_t)row * ldc + col] = f2b(e);
          rsum += e;
        }
#pragma unroll
        for (int off = 1; off < 16; off <<= 1) rsum += __shfl_xor(rsum, off);
        if (l15 == 0) atomicAdd(&rowsum[row], rsum);
      }
  } else if constexpr (MODE == 2) {
#pragma unroll
    for (int m = 0; m < 4; ++m)
#pragma unroll
      for (int n = 0; n < 4; ++n) {
        const int col = bx * 128 + wc * 64 + n * 16 + l15;
        const float bv = bias[col];
#pragma unroll
        for (int j = 0; j < 4; ++j) {
          const int row = by * 128 + wr * 64 + m * 16 + l4 * 4 + j;
          const float inv = 1.0f / rowsum[row];
          Cf[(size_t)row * ldc + col] = acc[m][n][j] * inv + bv;
        }
      }
  } else {
#pragma unroll
    for (int m = 0; m < 4; ++m)
#pragma unroll
      for (int n = 0; n < 4; ++n) {
        const int col = bx * 128 + wc * 64 + n * 16 + l15;
        const float bv = bias ? bias[col] : 0.f;
#pragma unroll
        for (int j = 0; j < 4; ++j) {
          const int row = by * 128 + wr * 64 + m * 16 + l4 * 4 + j;
          const float val = acc[m][n][j] * scale + bv;
          if (OUT_BF16) Cb[(size_t)row * ldc + col] = f2b(val);
          else          Cf[(size_t)row * ldc + col] = val;
        }
      }
  }
}

// ---------------------------------------------------------------------------
// wvo_bias2: blocks 0..63  -> WvoT_w[d][j] = sum_t Wot[d][t]*Wv[j][t]
//            blocks 64..127 -> bias2[col] = bo[col] + sum_r bv[r]*Wo[r][col]
// ---------------------------------------------------------------------------
__global__ __launch_bounds__(256)
void wvo_bias2(const unsigned short* __restrict__ Wot,
               const unsigned short* __restrict__ Wvb,
               const float* __restrict__ bv, const float* __restrict__ Wo,
               const float* __restrict__ bo,
               unsigned short* __restrict__ WvoT_w, float* __restrict__ bias2)
{
  if (blockIdx.x < 64) {
    gemm_body<true, 0>(Wot, Wvb, nullptr, WvoT_w, nullptr,
                       1024, 1024, 1024, 1024, 1.f,
                       (int)blockIdx.x & 7, (int)blockIdx.x >> 3);
    return;
  }
  __shared__ float red[16][17];
  const int b = blockIdx.x - 64;
  const int ci = threadIdx.x & 15;
  const int rg = threadIdx.x >> 4;
  const int col = b * 16 + ci;
  float s = 0.f;
#pragma unroll 4
  for (int r = rg; r < 1024; r += 16)
    s += bv[r] * Wo[(size_t)r * 1024 + col];
  red[rg][ci] = s;
  __syncthreads();
  if (rg == 0) {
    float t = 0.f;
#pragma unroll
    for (int i = 0; i < 16; ++i) t += red[i][ci];
    bias2[col] = t + bo[col];
  }
}

// ---------------------------------------------------------------------------
// gemm_qkv3, XCD-swizzled, 1536 blocks:
//  z0: qbuf = qin@Wq + bq          (by 0..63, bx 0..7, ldc 1024)
//  z1: kbuf = kin@Wk + bk
//  z2: vT[b][d][s] = sum_j WvoT_w[d][j]*vin[b][s][j]  (per-batch, ldc 2048)
// decode: xcd=d&7, j=d>>3, G=xcd*24+(j>>3).
// ---------------------------------------------------------------------------
__global__ __launch_bounds__(256)
void gemm_qkv3(const unsigned short* __restrict__ qin,
               const unsigned short* __restrict__ kin,
               const unsigned short* __restrict__ vin,
               const unsigned short* __restrict__ Wqt,
               const unsigned short* __restrict__ Wkt,
               const unsigned short* __restrict__ WvoT_w,
               const float* __restrict__ bq, const float* __restrict__ bk,
               unsigned short* __restrict__ qbuf, unsigned short* __restrict__ kbuf,
               unsigned short* __restrict__ vT)
{
  const int d = blockIdx.x;
  const int xcd = d & 7, j = d >> 3;
  const int G = xcd * 24 + (j >> 3);
  if (G < 64) {
    gemm_body<true, 0>(qin, Wqt, bq, qbuf, nullptr,
                       1024, 1024, 1024, 1024, 1.f, j & 7, G);
  } else if (G < 128) {
    gemm_body<true, 0>(kin, Wkt, bk, kbuf, nullptr,
                       1024, 1024, 1024, 1024, 1.f, j & 7, G - 64);
  } else {
    const int idx = (G - 128) * 8 + (j & 7);   // 0..511
    const int b  = idx >> 7;
    const int r  = idx & 127;
    const int by = r >> 4;    // d-tile 0..7
    const int bx = r & 15;    // s-tile 0..15
    gemm_body<true, 0>(WvoT_w, vin + (size_t)b * 2048 * 1024, nullptr,
                       vT + (size_t)b * 1024 * 2048, nullptr,
                       1024, 1024, 1024, 2048, 1.f, bx, by);
  }
}

// ---------------------------------------------------------------------------
// scores: E = exp(q k^T / 32) causal, bf16 dense [2048][2048] per batch,
// rowsum accumulated. 544 blocks = 8 XCD chunks x 68, triangular decode.
// ---------------------------------------------------------------------------
__global__ __launch_bounds__(256)
void gemm_scores(const unsigned short* __restrict__ Q,
                 const unsigned short* __restrict__ Kb,
                 unsigned short* __restrict__ P, float* __restrict__ rowsum)
{
  const int d = blockIdx.x;
  const int t = (d & 7) * 68 + (d >> 3);
  const int bz = t / 136;
  const int tri = t - bz * 136;
  int by = (int)((sqrtf(8.f * tri + 1.f) - 1.f) * 0.5f);
  while ((by + 1) * (by + 2) / 2 <= tri) ++by;
  while (by * (by + 1) / 2 > tri) --by;
  const int bx = tri - by * (by + 1) / 2;
  gemm_body<true, 1>(Q + (size_t)bz * 2048 * 1024,
                     Kb + (size_t)bz * 2048 * 1024, nullptr,
                     P + (size_t)bz * 2048 * 2048,
                     rowsum + (size_t)bz * 2048,
                     1024, 1024, 1024, 2048, 0.03125f, bx, by);
}

// ---------------------------------------------------------------------------
// final: out = (E @ vT) / rowsum + bias2 -> fp32 d_out. 512 blocks,
// XCD-swizzled, causal K-limit kEnd=(by+1)*128.
// ---------------------------------------------------------------------------
__global__ __launch_bounds__(256)
void gemm_final(const unsigned short* __restrict__ P,
                const unsigned short* __restrict__ vT,
                const float* __restrict__ bias2, float* __restrict__ rowsum,
                float* __restrict__ out)
{
  const int d = blockIdx.x;
  const int xcd = d & 7, j = d >> 3;
  const int G = xcd * 8 + (j >> 3);
  const int bz = G >> 4;
  const int by = G & 15;
  const int bx = j & 7;
  const int kEnd = (by + 1) * 128;
  gemm_body<false, 2>(P + (size_t)bz * 2048 * 2048,
                      vT + (size_t)bz * 1024 * 2048, bias2,
                      out + (size_t)bz * 2048 * 1024,
                      rowsum + (size_t)bz * 2048,
                      kEnd, 2048, 2048, 1024, 1.f, bx, by);
}

// ---------------------------------------------------------------------------
extern "C" void kernel_launch(void* const* d_in, const int* in_sizes, int n_in,
                              void* d_out, int out_size, void* d_ws, size_t ws_size,
                              hipStream_t stream)
{
  const float* query = (const float*)d_in[0];
  const float* key   = (const float*)d_in[1];
  const float* value = (const float*)d_in[2];
  const float* Wq    = (const float*)d_in[3];
  const float* bq    = (const float*)d_in[4];
  const float* Wk    = (const float*)d_in[5];
  const float* bk    = (const float*)d_in[6];
  const float* Wv    = (const float*)d_in[7];
  const float* bv    = (const float*)d_in[8];
  const float* Wo    = (const float*)d_in[9];
  const float* bo    = (const float*)d_in[10];
  float* out = (float*)d_out;

  char* ws = (char*)d_ws;
  const size_t MB = 1024 * 1024;
  unsigned short* Wqt    = (unsigned short*)(ws + 0 * MB);
  unsigned short* Wkt    = (unsigned short*)(ws + 2 * MB);
  unsigned short* Wot    = (unsigned short*)(ws + 4 * MB);
  unsigned short* Wvb    = (unsigned short*)(ws + 6 * MB);
  unsigned short* WvoT_w = (unsigned short*)(ws + 8 * MB);
  float*          bias2  = (float*)(ws + 10 * MB);
  float*          rowsum = (float*)(ws + 11 * MB);          // 32 KB
  unsigned short* qbuf   = (unsigned short*)(ws + 12 * MB); // 16 MB
  unsigned short* kbuf   = (unsigned short*)(ws + 28 * MB); // 16 MB
  unsigned short* vT     = (unsigned short*)(ws + 44 * MB); // 16 MB
  unsigned short* qin    = (unsigned short*)(ws + 60 * MB); // 16 MB
  unsigned short* kin    = (unsigned short*)(ws + 76 * MB); // 16 MB
  unsigned short* vin    = (unsigned short*)(ws + 92 * MB); // 16 MB
  unsigned short* Pbuf   = (unsigned short*)(ws + 108 * MB);// 32 MB

  // rowsum <- 0 (32 KB), graph-capturable
  hipMemsetAsync(rowsum, 0, 4 * 2048 * sizeof(float), stream);

  // 1) input casts + weight prep (merged)
  prep_all<<<16384, 256, 0, stream>>>(query, key, value, qin, kin, vin,
                                      Wq, Wk, Wo, Wv, Wqt, Wkt, Wot, Wvb);

  // 2) WvoT_w = (Wv@Wo)^T  +  bias2 = bv@Wo + bo (merged)
  wvo_bias2<<<128, 256, 0, stream>>>(Wot, Wvb, bv, Wo, bo, WvoT_w, bias2);

  // 3) fused projections: q@Wq+bq, k@Wk+bk, vT = Wvo^T·v^T (XCD-swizzled)
  gemm_qkv3<<<1536, 256, 0, stream>>>(qin, kin, vin, Wqt, Wkt, WvoT_w,
                                      bq, bk, qbuf, kbuf, vT);

  // 4) E = exp(q k^T/32) causal, bf16 + rowsum (packed triangular, swizzled)
  gemm_scores<<<544, 256, 0, stream>>>(qbuf, kbuf, Pbuf, rowsum);

  // 5) out = (E @ vT)/rowsum + bias2 -> fp32 d_out
  gemm_final<<<512, 256, 0, stream>>>(Pbuf, vT, bias2, rowsum, out);
}

// Round 11
// 328.947 us; speedup vs baseline: 1.2734x; 1.0102x over previous
//
#include <hip/hip_runtime.h>

// ---------------------------------------------------------------------------
// Fused single-head causal attention (B=4, S=2048, D=1024), fp32 in/out.
// Folds: Wvo=Wv@Wo, bias2=bv@Wo+bo  =>  out = P@(v@Wvo)+bias2 (exact).
// No-max softmax: E=exp(s) in scores epilogue, rowsum via atomicAdd,
// normalization folded into final GEMM epilogue. (validated R8, absmax .023)
// Residency-balanced grids: every dispatch <= 1280 co-resident blocks
// (5/CU at 32KB LDS), uniform work per CU; final uses complementary
// (by, 15-by) pairing so per-CU K-step sums are constant (=17).
// 5 dispatches: memset -> prep_all -> qk+wvo+bias2 -> scores+vT -> final.
// GEMM: 128x128 tile, BK=64, global_load_lds both operands, XOR-swizzled LDS.
// ---------------------------------------------------------------------------

typedef __attribute__((ext_vector_type(8))) short bf16x8_t;   // 8 bf16 = 4 VGPR
typedef __attribute__((ext_vector_type(4))) float f32x4_t;    // MFMA acc

static __device__ __forceinline__ unsigned short f2b(float f) {
  union { float f; unsigned u; } c; c.f = f;
  unsigned u = c.u;
  u += 0x7fffu + ((u >> 16) & 1u);   // round-to-nearest-even
  return (unsigned short)(u >> 16);
}

static __device__ __forceinline__ void gload16(const void* g, const void* l) {
  __builtin_amdgcn_global_load_lds(
      (const __attribute__((address_space(1))) void*)g,
      (__attribute__((address_space(3))) void*)(void*)(unsigned short*)l,
      16, 0, 0);
}

// ---------------------------------------------------------------------------
// prep_all: merged input casts + weight prep.
//  d < 12288 : cast q/k/v fp32->bf16 (z=d>>12, 8 elem/thread)
//  d >= 12288: t=d-12288; z=t>>10: 0=Wq^T,1=Wk^T,2=Wo^T (transpose+cast),
//              3=Wv straight cast.
// ---------------------------------------------------------------------------
__global__ __launch_bounds__(256)
void prep_all(const float* __restrict__ q, const float* __restrict__ k,
              const float* __restrict__ v,
              unsigned short* __restrict__ qin, unsigned short* __restrict__ kin,
              unsigned short* __restrict__ vin,
              const float* __restrict__ wq, const float* __restrict__ wk,
              const float* __restrict__ wo, const float* __restrict__ wv,
              unsigned short* __restrict__ oq, unsigned short* __restrict__ ok,
              unsigned short* __restrict__ oo, unsigned short* __restrict__ ov)
{
  __shared__ unsigned short t[32][34];
  const int d = blockIdx.x;
  const int tid = threadIdx.x;
  if (d < 12288) {
    const int z = d >> 12;
    const int blk = d & 4095;
    const float* in = z == 0 ? q : (z == 1 ? k : v);
    unsigned short* out = z == 0 ? qin : (z == 1 ? kin : vin);
    const size_t base = ((size_t)blk * 256 + tid) * 8;
    const float4 x0 = *(const float4*)(in + base);
    const float4 x1 = *(const float4*)(in + base + 4);
    union { unsigned u[4]; uint4 v4; } pk;
    pk.u[0] = f2b(x0.x) | ((unsigned)f2b(x0.y) << 16);
    pk.u[1] = f2b(x0.z) | ((unsigned)f2b(x0.w) << 16);
    pk.u[2] = f2b(x1.x) | ((unsigned)f2b(x1.y) << 16);
    pk.u[3] = f2b(x1.z) | ((unsigned)f2b(x1.w) << 16);
    *(uint4*)(out + base) = pk.v4;
    return;
  }
  const int tt = d - 12288;
  const int z = tt >> 10;
  const int r = tt & 1023;
  const int by = r >> 5, bx = r & 31;
  const int x = tid & 31, y = tid >> 5;
  const float* in = z == 0 ? wq : (z == 1 ? wk : (z == 2 ? wo : wv));
  unsigned short* out = z == 0 ? oq : (z == 1 ? ok : (z == 2 ? oo : ov));
  if (z == 3) {   // straight cast
#pragma unroll
    for (int yy = y; yy < 32; yy += 8) {
      const int rr = by * 32 + yy, cc = bx * 32 + x;
      out[(size_t)rr * 1024 + cc] = f2b(in[(size_t)rr * 1024 + cc]);
    }
    return;
  }
#pragma unroll
  for (int yy = y; yy < 32; yy += 8)
    t[yy][x] = f2b(in[(size_t)(by * 32 + yy) * 1024 + bx * 32 + x]);
  __syncthreads();
#pragma unroll
  for (int yy = y; yy < 32; yy += 8)
    out[(size_t)(bx * 32 + yy) * 1024 + by * 32 + x] = t[x][yy];
}

// ---------------------------------------------------------------------------
// GEMM body (LDS passed in): 128x128 tile, BK=64, gload_lds both operands.
// MODE 0: C = scale*A·Bt^T (+bias).  MODE 1: scores-exp + rowsum atomics.
// MODE 2: final-norm Cf = acc/rowsum[row] + bias[col].
// 16B-chunk swizzle chunk^=row&7 on BOTH global source and ds_read addr.
// ---------------------------------------------------------------------------
template<bool OUT_BF16, int MODE>
static __device__ __forceinline__
void gemm_body(unsigned short* __restrict__ As, unsigned short* __restrict__ Bs,
               const unsigned short* __restrict__ Ab,
               const unsigned short* __restrict__ Bt,
               const float* __restrict__ bias, void* __restrict__ Cp,
               float* __restrict__ rowsum,
               int kEnd, int lda, int ldb, int ldc, float scale, int bx, int by)
{
  const int tid  = threadIdx.x;
  const int lane = tid & 63;
  const int wid  = tid >> 6;
  const int wr   = wid >> 1, wc = wid & 1;
  const int l15  = lane & 15, l4 = lane >> 4;

  const int srow_l = lane >> 3;   // gload: lane -> row within 8-row group
  const int schk   = lane & 7;    // gload: 16B chunk

  f32x4_t acc[4][4];
#pragma unroll
  for (int m = 0; m < 4; ++m)
#pragma unroll
    for (int n = 0; n < 4; ++n) acc[m][n] = (f32x4_t){0.f, 0.f, 0.f, 0.f};

  for (int k0 = 0; k0 < kEnd; k0 += 64) {
#pragma unroll
    for (int i = 0; i < 4; ++i) {
      const int row = i * 32 + wid * 8 + srow_l;
      const size_t gr = (size_t)(by * 128 + row);
      const int g = schk ^ (row & 7);
      gload16(Ab + gr * lda + k0 + g * 8, &As[(i * 32 + wid * 8) * 64]);
    }
#pragma unroll
    for (int i = 0; i < 4; ++i) {
      const int row = i * 32 + wid * 8 + srow_l;
      const size_t gn = (size_t)(bx * 128 + row);
      const int g = schk ^ (row & 7);
      gload16(Bt + gn * ldb + k0 + g * 8, &Bs[(i * 32 + wid * 8) * 64]);
    }
    __syncthreads();

#pragma unroll
    for (int kk = 0; kk < 2; ++kk) {
      bf16x8_t a[4], b[4];
#pragma unroll
      for (int m = 0; m < 4; ++m) {
        const int row = wr * 64 + m * 16 + l15;
        const int c = (kk * 4 + l4) ^ (row & 7);
        a[m] = *(const bf16x8_t*)&As[row * 64 + c * 8];
      }
#pragma unroll
      for (int n = 0; n < 4; ++n) {
        const int row = wc * 64 + n * 16 + l15;
        const int c = (kk * 4 + l4) ^ (row & 7);
        b[n] = *(const bf16x8_t*)&Bs[row * 64 + c * 8];
      }
#pragma unroll
      for (int m = 0; m < 4; ++m)
#pragma unroll
        for (int n = 0; n < 4; ++n)
          acc[m][n] = __builtin_amdgcn_mfma_f32_16x16x32_bf16(a[m], b[n], acc[m][n], 0, 0, 0);
    }
    __syncthreads();
  }

  // epilogue: C/D layout col = lane&15, row = (lane>>4)*4 + j
  float*          Cf = (float*)Cp;
  unsigned short* Cb = (unsigned short*)Cp;
  if constexpr (MODE == 1) {
#pragma unroll
    for (int m = 0; m < 4; ++m)
#pragma unroll
      for (int j = 0; j < 4; ++j) {
        const int row = by * 128 + wr * 64 + m * 16 + l4 * 4 + j;
        float rsum = 0.f;
#pragma unroll
        for (int n = 0; n < 4; ++n) {
          const int col = bx * 128 + wc * 64 + n * 16 + l15;
          const float e = (col <= row) ? __expf(acc[m][n][j] * scale) : 0.f;
          Cb[(size_t)row * ldc + col] = f2b(e);
          rsum += e;
        }
#pragma unroll
        for (int off = 1; off < 16; off <<= 1) rsum += __shfl_xor(rsum, off);
        if (l15 == 0) atomicAdd(&rowsum[row], rsum);
      }
  } else if constexpr (MODE == 2) {
#pragma unroll
    for (int m = 0; m < 4; ++m)
#pragma unroll
      for (int n = 0; n < 4; ++n) {
        const int col = bx * 128 + wc * 64 + n * 16 + l15;
        const float bv = bias[col];
#pragma unroll
        for (int j = 0; j < 4; ++j) {
          const int row = by * 128 + wr * 64 + m * 16 + l4 * 4 + j;
          const float inv = 1.0f / rowsum[row];
          Cf[(size_t)row * ldc + col] = acc[m][n][j] * inv + bv;
        }
      }
  } else {
#pragma unroll
    for (int m = 0; m < 4; ++m)
#pragma unroll
      for (int n = 0; n < 4; ++n) {
        const int col = bx * 128 + wc * 64 + n * 16 + l15;
        const float bv = bias ? bias[col] : 0.f;
#pragma unroll
        for (int j = 0; j < 4; ++j) {
          const int row = by * 128 + wr * 64 + m * 16 + l4 * 4 + j;
          const float val = acc[m][n][j] * scale + bv;
          if (OUT_BF16) Cb[(size_t)row * ldc + col] = f2b(val);
          else          Cf[(size_t)row * ldc + col] = val;
        }
      }
  }
}

// ---------------------------------------------------------------------------
// qk+wvo+bias2, 1152 blocks (<=1280 resident, uniform 16-step jobs):
//  d<1024  : q/k proj. xcd=d&7, j=d>>3, G=xcd*16+(j>>3): z=G>>6, by=G&63,
//            bx=j&7. XCDs 0-3 own q-panels, 4-7 own k-panels (L2 reuse).
//  d<1088  : WvoT_w = (Wv@Wo)^T tile (w=d-1024: bx=w&7, by=w>>3)
//  d<1152  : bias2[col] GEMV (reuses As as the reduction scratch)
// ---------------------------------------------------------------------------
__global__ __launch_bounds__(256)
void gemm_qk_wvo(const unsigned short* __restrict__ qin,
                 const unsigned short* __restrict__ kin,
                 const unsigned short* __restrict__ Wqt,
                 const unsigned short* __restrict__ Wkt,
                 const unsigned short* __restrict__ Wot,
                 const unsigned short* __restrict__ Wvb,
                 const float* __restrict__ bq, const float* __restrict__ bk,
                 const float* __restrict__ bv, const float* __restrict__ Wo,
                 const float* __restrict__ bo,
                 unsigned short* __restrict__ qbuf,
                 unsigned short* __restrict__ kbuf,
                 unsigned short* __restrict__ WvoT_w,
                 float* __restrict__ bias2)
{
  __shared__ unsigned short As[128 * 64];
  __shared__ unsigned short Bs[128 * 64];
  const int d = blockIdx.x;
  if (d < 1024) {
    const int xcd = d & 7, j = d >> 3;
    const int G = xcd * 16 + (j >> 3);     // 0..127
    const int z = G >> 6;                  // 0=q, 1=k
    const int by = G & 63, bx = j & 7;
    if (z == 0)
      gemm_body<true, 0>(As, Bs, qin, Wqt, bq, qbuf, nullptr,
                         1024, 1024, 1024, 1024, 1.f, bx, by);
    else
      gemm_body<true, 0>(As, Bs, kin, Wkt, bk, kbuf, nullptr,
                         1024, 1024, 1024, 1024, 1.f, bx, by);
    return;
  }
  if (d < 1088) {
    const int w = d - 1024;
    gemm_body<true, 0>(As, Bs, Wot, Wvb, nullptr, WvoT_w, nullptr,
                       1024, 1024, 1024, 1024, 1.f, w & 7, w >> 3);
    return;
  }
  // bias2[col] = bo[col] + sum_r bv[r]*Wo[r][col]; 64 blocks x 16 cols
  float* red = (float*)As;                 // [16][17]
  const int b = d - 1088;
  const int ci = threadIdx.x & 15;
  const int rg = threadIdx.x >> 4;
  const int col = b * 16 + ci;
  float s = 0.f;
#pragma unroll 4
  for (int r = rg; r < 1024; r += 16)
    s += bv[r] * Wo[(size_t)r * 1024 + col];
  red[rg * 17 + ci] = s;
  __syncthreads();
  if (rg == 0) {
    float t = 0.f;
#pragma unroll
    for (int i = 0; i < 16; ++i) t += red[i * 17 + ci];
    bias2[col] = t + bo[col];
  }
}

// ---------------------------------------------------------------------------
// scores+vT, 1056 blocks (all resident, uniform 16-step jobs):
//  d<544 : E = exp(q k^T/32) causal + rowsum (triangular XCD decode)
//  d>=544: vT[b][dd][s] = sum_j WvoT_w[dd][j]*vin[b][s][j]  (512 jobs)
// ---------------------------------------------------------------------------
__global__ __launch_bounds__(256)
void gemm_scores_vt(const unsigned short* __restrict__ Q,
                    const unsigned short* __restrict__ Kb,
                    const unsigned short* __restrict__ vin,
                    const unsigned short* __restrict__ WvoT_w,
                    unsigned short* __restrict__ P, float* __restrict__ rowsum,
                    unsigned short* __restrict__ vT)
{
  __shared__ unsigned short As[128 * 64];
  __shared__ unsigned short Bs[128 * 64];
  const int d = blockIdx.x;
  if (d < 544) {
    const int t = (d & 7) * 68 + (d >> 3);
    const int bz = t / 136;
    const int tri = t - bz * 136;
    int by = (int)((sqrtf(8.f * tri + 1.f) - 1.f) * 0.5f);
    while ((by + 1) * (by + 2) / 2 <= tri) ++by;
    while (by * (by + 1) / 2 > tri) --by;
    const int bx = tri - by * (by + 1) / 2;
    gemm_body<true, 1>(As, Bs, Q + (size_t)bz * 2048 * 1024,
                       Kb + (size_t)bz * 2048 * 1024, nullptr,
                       P + (size_t)bz * 2048 * 2048,
                       rowsum + (size_t)bz * 2048,
                       1024, 1024, 1024, 2048, 0.03125f, bx, by);
    return;
  }
  const int e = d - 544;                   // 0..511
  const int xcd = e & 7, j = e >> 3;
  const int jj = (xcd * 8 + (j >> 3)) * 8 + (j & 7);   // 0..511
  const int b  = jj >> 7;
  const int r  = jj & 127;
  const int by = r >> 4;    // d-tile 0..7
  const int bx = r & 15;    // s-tile 0..15
  gemm_body<true, 0>(As, Bs, WvoT_w, vin + (size_t)b * 2048 * 1024, nullptr,
                     vT + (size_t)b * 1024 * 2048, nullptr,
                     1024, 1024, 1024, 2048, 1.f, bx, by);
}

// ---------------------------------------------------------------------------
// final: out = (E @ vT)/rowsum + bias2 -> fp32. 512 blocks, all co-resident;
// complementary pairing: CU cohabitants (slots s, s+4 of an XCD) get by and
// 15-by, so per-CU K-step work is constant (17). kEnd=(by+1)*128.
// decode: xcd=d&7; j=d>>3; s=j>>3; bx=j&7; w=s*8+xcd;
//         by = w<32 ? 15-(w>>2) : (w-32)>>2;  bz = w&3.
// ---------------------------------------------------------------------------
__global__ __launch_bounds__(256)
void gemm_final(const unsigned short* __restrict__ P,
                const unsigned short* __restrict__ vT,
                const float* __restrict__ bias2, float* __restrict__ rowsum,
                float* __restrict__ out)
{
  __shared__ unsigned short As[128 * 64];
  __shared__ unsigned short Bs[128 * 64];
  const int d = blockIdx.x;
  const int xcd = d & 7, j = d >> 3;
  const int s = j >> 3, bx = j & 7;
  const int w = s * 8 + xcd;               // 0..63
  const int by = (w < 32) ? (15 - (w >> 2)) : ((w - 32) >> 2);
  const int bz = w & 3;
  const int kEnd = (by + 1) * 128;
  gemm_body<false, 2>(As, Bs, P + (size_t)bz * 2048 * 2048,
                      vT + (size_t)bz * 1024 * 2048, bias2,
                      out + (size_t)bz * 2048 * 1024,
                      rowsum + (size_t)bz * 2048,
                      kEnd, 2048, 2048, 1024, 1.f, bx, by);
}

// ---------------------------------------------------------------------------
extern "C" void kernel_launch(void* const* d_in, const int* in_sizes, int n_in,
                              void* d_out, int out_size, void* d_ws, size_t ws_size,
                              hipStream_t stream)
{
  const float* query = (const float*)d_in[0];
  const float* key   = (const float*)d_in[1];
  const float* value = (const float*)d_in[2];
  const float* Wq    = (const float*)d_in[3];
  const float* bq    = (const float*)d_in[4];
  const float* Wk    = (const float*)d_in[5];
  const float* bk    = (const float*)d_in[6];
  const float* Wv    = (const float*)d_in[7];
  const float* bv    = (const float*)d_in[8];
  const float* Wo    = (const float*)d_in[9];
  const float* bo    = (const float*)d_in[10];
  float* out = (float*)d_out;

  char* ws = (char*)d_ws;
  const size_t MB = 1024 * 1024;
  unsigned short* Wqt    = (unsigned short*)(ws + 0 * MB);
  unsigned short* Wkt    = (unsigned short*)(ws + 2 * MB);
  unsigned short* Wot    = (unsigned short*)(ws + 4 * MB);
  unsigned short* Wvb    = (unsigned short*)(ws + 6 * MB);
  unsigned short* WvoT_w = (unsigned short*)(ws + 8 * MB);
  float*          bias2  = (float*)(ws + 10 * MB);
  float*          rowsum = (float*)(ws + 11 * MB);          // 32 KB
  unsigned short* qbuf   = (unsigned short*)(ws + 12 * MB); // 16 MB
  unsigned short* kbuf   = (unsigned short*)(ws + 28 * MB); // 16 MB
  unsigned short* vT     = (unsigned short*)(ws + 44 * MB); // 16 MB
  unsigned short* qin    = (unsigned short*)(ws + 60 * MB); // 16 MB
  unsigned short* kin    = (unsigned short*)(ws + 76 * MB); // 16 MB
  unsigned short* vin    = (unsigned short*)(ws + 92 * MB); // 16 MB
  unsigned short* Pbuf   = (unsigned short*)(ws + 108 * MB);// 32 MB

  // rowsum <- 0 (32 KB), graph-capturable
  hipMemsetAsync(rowsum, 0, 4 * 2048 * sizeof(float), stream);

  // 1) input casts + weight prep (merged)
  prep_all<<<16384, 256, 0, stream>>>(query, key, value, qin, kin, vin,
                                      Wq, Wk, Wo, Wv, Wqt, Wkt, Wot, Wvb);

  // 2) q/k projections + WvoT + bias2 (one dispatch, 1152 blocks)
  gemm_qk_wvo<<<1152, 256, 0, stream>>>(qin, kin, Wqt, Wkt, Wot, Wvb,
                                        bq, bk, bv, Wo, bo,
                                        qbuf, kbuf, WvoT_w, bias2);

  // 3) scores (E=exp, causal, rowsum) + vT GEMM (one dispatch, 1056 blocks)
  gemm_scores_vt<<<1056, 256, 0, stream>>>(qbuf, kbuf, vin, WvoT_w,
                                           Pbuf, rowsum, vT);

  // 4) out = (E @ vT)/rowsum + bias2 (512 blocks, pair-balanced)
  gemm_final<<<512, 256, 0, stream>>>(Pbuf, vT, bias2, rowsum, out);
}